// Round 10
// baseline (259.327 us; speedup 1.0000x reference)
//
#include <hip/hip_runtime.h>
#include <math.h>

typedef unsigned short u16;
typedef __attribute__((ext_vector_type(8))) short short8;
typedef __attribute__((ext_vector_type(4))) float floatx4;

constexpr int BATCH = 16;
constexpr int NI = 1024;
constexpr int CE = 64;
constexpr int CI = 16;
constexpr long long NN2  = (long long)NI * NI;          // 1M
constexpr long long BCN  = (long long)BATCH * CE * NI;  // 1M
constexpr long long BNv  = (long long)BATCH * NI;       // 16K
constexpr long long BNN  = (long long)BATCH * NI * NI;  // 16M
constexpr long long S1 = (long long)CE * NI;            // 65536
constexpr long long S2 = 2 * S1;                        // 131072

__device__ __forceinline__ float lrelu01(float x) { return x > 0.f ? x : 0.01f * x; }

__device__ __forceinline__ u16 f2bf(float f) {
  unsigned u = __builtin_bit_cast(unsigned, f);
  return (u16)((u + 0x7fffu + ((u >> 16) & 1u)) >> 16);  // RNE
}
__device__ __forceinline__ float bf2f(u16 h) {
  unsigned u = ((unsigned)h) << 16;
  return __builtin_bit_cast(float, u);
}
// monotonic uint key for float atomicMax (memset-0 init safe: real-float keys > 0)
__device__ __forceinline__ unsigned fkey(float f) {
  unsigned u = __builtin_bit_cast(unsigned, f);
  return (u & 0x80000000u) ? ~u : (u | 0x80000000u);
}
__device__ __forceinline__ float funkey(unsigned k) {
  unsigned u = (k & 0x80000000u) ? (k & 0x7fffffffu) : ~k;
  return __builtin_bit_cast(float, u);
}

// ================= MFMA TN GEMM: C[r][m] = sum_k A[r][k] * Bt[m][k] ==============
// A, Bt bf16 row-major K-contiguous. BK=64, XOR-swizzled 16B chunks in LDS.
// 4 waves 2x2; wave tile (BM/2)x(BN/2); 16x16x32 MFMAs.
// MODE: 3 gram exp + rowsum | 4 Abig scatter w/ Z-div |
//       5 dual-B + rank-1 epilogue + LN-stats atomics | 6 plain bf16 |
//       13 A = attention-p on the fly + in-block invZ + relu + second MFMA stage |
//       14 hT direct: +rank-1 (wcs x emb2_b) + per-column s1/s2 dots + s2max
template<int BM, int BN, int MODE>
__global__ __launch_bounds__(256) void mgemm(
    const u16* __restrict__ Ag, const u16* __restrict__ B1g, const u16* __restrict__ B2g,
    int K1, int K, int lda, int ldb, long long bsA, long long bsB1,
    float* __restrict__ Cf, u16* __restrict__ Cb, int ldc, long long bsC,
    const float* __restrict__ aux1, const float* __restrict__ aux2,
    const float* __restrict__ aux3, const float* __restrict__ aux4,
    float* __restrict__ Zout)
{
  constexpr int RM = BM / 2, RN = BN / 2, MI = RM / 16, NJ = RN / 16;
  __shared__ __align__(16) u16 As[BM * 64];
  __shared__ __align__(16) u16 Bs[BN * 64];
  __shared__ __align__(16) u16 xa[MODE == 13 ? 32 * 72 : 1];  // stage-2 A tile (padded)
  const int z = blockIdx.z;
  const int n0 = blockIdx.x * BN;
  const int r0 = blockIdx.y * BM;
  const u16* Ab = Ag + (long long)z * bsA + (long long)r0 * lda;
  const u16* Bb1 = B1g + (long long)z * bsB1 + (long long)n0 * ldb;
  const int tid = threadIdx.x;
  const int lane = tid & 63;
  const int wid = tid >> 6;
  const int wr = wid >> 1, wc = wid & 1;
  const int q = lane >> 4, mlow = lane & 15;

  floatx4 acc[MI][NJ] = {};
  float zp[(BM * 8) / 256] = {};       // MODE13 row p-sums

  for (int k0 = 0; k0 < K; k0 += 64) {
    if constexpr (MODE == 13) {
      // A-tile = attention p from s1 (aux2), s2 (aux3), s2max key (aux4)
      const float* s1z = aux2 + (long long)z * NI;
      const float* s2z = aux3 + (long long)z * NI;
      const float mb = funkey(((const unsigned*)aux4)[z]);
#pragma unroll
      for (int s = 0; s < (BM * 8) / 256; s++) {
        int cid = tid + s * 256;
        int r = cid >> 3, craw = cid & 7;
        float s1r = s1z[r0 + r];
        float mr = lrelu01(s1r + mb);
        const float* sp = s2z + k0 + craw * 8;
        float4 sa = *(const float4*)sp;
        float4 sb = *(const float4*)(sp + 4);
        float p0 = __expf(lrelu01(s1r + sa.x) - mr);
        float p1 = __expf(lrelu01(s1r + sa.y) - mr);
        float p2 = __expf(lrelu01(s1r + sa.z) - mr);
        float p3 = __expf(lrelu01(s1r + sa.w) - mr);
        float p4 = __expf(lrelu01(s1r + sb.x) - mr);
        float p5 = __expf(lrelu01(s1r + sb.y) - mr);
        float p6 = __expf(lrelu01(s1r + sb.z) - mr);
        float p7 = __expf(lrelu01(s1r + sb.w) - mr);
        zp[s] += p0 + p1 + p2 + p3 + p4 + p5 + p6 + p7;
        uint4 v;
        v.x = (unsigned)f2bf(p0) | ((unsigned)f2bf(p1) << 16);
        v.y = (unsigned)f2bf(p2) | ((unsigned)f2bf(p3) << 16);
        v.z = (unsigned)f2bf(p4) | ((unsigned)f2bf(p5) << 16);
        v.w = (unsigned)f2bf(p6) | ((unsigned)f2bf(p7) << 16);
        *(uint4*)&As[(r * 8 + (craw ^ (r & 7))) * 8] = v;
      }
    } else {
      const u16* Asrc = Ab + k0;
#pragma unroll
      for (int s = 0; s < (BM * 8) / 256; s++) {
        int cid = tid + s * 256;
        int r = cid >> 3, craw = cid & 7;
        uint4 v = *(const uint4*)(Asrc + (long long)r * lda + craw * 8);
        *(uint4*)&As[(r * 8 + (craw ^ (r & 7))) * 8] = v;
      }
    }
    {
      const u16* Bsrc = (k0 < K1) ? (Bb1 + k0)
                                  : (B2g + (long long)n0 * ldb + (k0 - K1));
#pragma unroll
      for (int s = 0; s < (BN * 8) / 256; s++) {
        int cid = tid + s * 256;
        int r = cid >> 3, craw = cid & 7;
        uint4 v = *(const uint4*)(Bsrc + (long long)r * ldb + craw * 8);
        *(uint4*)&Bs[(r * 8 + (craw ^ (r & 7))) * 8] = v;
      }
    }
    __syncthreads();
#pragma unroll
    for (int kh = 0; kh < 2; kh++) {
      const int kc = kh * 4 + q;
      short8 afr[MI], bfr[NJ];
#pragma unroll
      for (int i = 0; i < MI; i++) {
        int row = wr * RM + i * 16 + mlow;
        afr[i] = *(const short8*)&As[(row * 8 + (kc ^ (row & 7))) * 8];
      }
#pragma unroll
      for (int j = 0; j < NJ; j++) {
        int row = wc * RN + j * 16 + mlow;
        bfr[j] = *(const short8*)&Bs[(row * 8 + (kc ^ (row & 7))) * 8];
      }
#pragma unroll
      for (int i = 0; i < MI; i++)
#pragma unroll
        for (int j = 0; j < NJ; j++)
          acc[i][j] = __builtin_amdgcn_mfma_f32_16x16x32_bf16(afr[i], bfr[j], acc[i][j], 0, 0, 0);
    }
    __syncthreads();
  }

  if constexpr (MODE == 3) {
    const float* sqb = aux1 + (long long)z * NI;
#pragma unroll
    for (int i = 0; i < MI; i++) {
#pragma unroll
      for (int rg = 0; rg < 4; rg++) {
        int r = r0 + wr * RM + i * 16 + q * 4 + rg;
        float sqi = sqb[r];
        float rsum = 0.f;
#pragma unroll
        for (int j = 0; j < NJ; j++) {
          int ncol = n0 + wc * RN + j * 16 + mlow;
          float d2 = fmaxf(sqi + sqb[ncol] - 2.f * acc[i][j][rg], 0.f);
          float w = __expf(__expf(-d2 * (1.f / 128.f)) + (r == ncol ? 1.f : 0.f) - 2.f);
          Cb[(long long)z * bsC + (long long)r * ldc + ncol] = f2bf(w);
          rsum += w;
        }
        rsum += __shfl_xor(rsum, 1);
        rsum += __shfl_xor(rsum, 2);
        rsum += __shfl_xor(rsum, 4);
        rsum += __shfl_xor(rsum, 8);
        if (mlow == 0) atomicAdd(&Zout[(long long)z * NI + r], rsum);
      }
    }
  } else if constexpr (MODE == 14) {
    // hT write + rank-1 bias (wcs=aux3 x emb2_b=aux1) + column dots w/ atta (aux2)
    float ps1 = 0.f, ps2 = 0.f;
#pragma unroll
    for (int i = 0; i < MI; i++) {
#pragma unroll
      for (int rg = 0; rg < 4; rg++) {
        int r = wr * RM + i * 16 + q * 4 + rg;  // r0 == 0 (grid.y == 1)
        int ncol = n0 + wc * RN + mlow;
        float v = acc[i][0][rg] + aux3[r] * aux1[ncol];
        Cb[(long long)z * bsC + (long long)r * ldc + ncol] = f2bf(v);
        ps1 = fmaf(v, aux2[r], ps1);
        ps2 = fmaf(v, aux2[64 + r], ps2);
      }
    }
    ps1 += __shfl_xor(ps1, 16); ps1 += __shfl_xor(ps1, 32);
    ps2 += __shfl_xor(ps2, 16); ps2 += __shfl_xor(ps2, 32);
    float* sred = (float*)As;  // s1: [32 cols][2 wr]; s2 at +64
    const int col = wc * RN + mlow;
    if (q == 0) { sred[col * 2 + wr] = ps1; sred[64 + col * 2 + wr] = ps2; }
    __syncthreads();
    if (tid < 32) {
      float v1 = sred[tid * 2] + sred[tid * 2 + 1];
      float v2 = sred[64 + tid * 2] + sred[64 + tid * 2 + 1];
      Cf[(long long)z * NI + n0 + tid] = v1;
      Zout[(long long)z * NI + n0 + tid] = v2;
      float mx = v2;
      for (int off = 1; off < 32; off <<= 1) mx = fmaxf(mx, __shfl_xor(mx, off));
      if (tid == 0) atomicMax((unsigned*)B2g + z, fkey(mx));
    }
  } else if constexpr (MODE == 13) {
    // ---- stage-1 finish: in-block softmax denominator (BM=32) ----
    float* zred = (float*)xa;            // [32][8]
    float* zinv = (float*)xa + 256;      // [32]
    zred[(tid >> 3) * 8 + (tid & 7)] = zp[0];
    __syncthreads();
    if (tid < 32) {
      float sum = 0.f;
#pragma unroll
      for (int j = 0; j < 8; j++) sum += zred[tid * 8 + j];
      zinv[tid] = 1.f / sum;
    }
    __syncthreads();
    float zr[4];
#pragma unroll
    for (int rg = 0; rg < 4; rg++) zr[rg] = zinv[wr * 16 + q * 4 + rg];
    __syncthreads();  // all zinv reads done before xa overwrite
    // ---- x_att tile (relu, scaled) -> xa as A-fragments; uaiw -> Bs ----
#pragma unroll
    for (int j = 0; j < NJ; j++) {
#pragma unroll
      for (int rg = 0; rg < 4; rg++) {
        int row = wr * 16 + q * 4 + rg;
        int col = wc * RN + j * 16 + mlow;
        float v = fmaxf(acc[0][j][rg] * zr[rg], 0.f);
        xa[row * 72 + col] = f2bf(v);
      }
    }
#pragma unroll
    for (int s = 0; s < 2; s++) {
      int cid = tid + s * 256;
      int r = cid >> 3, craw = cid & 7;
      *(uint4*)&Bs[(r * 8 + (craw ^ (r & 7))) * 8] =
          *(const uint4*)(B2g + r * 64 + craw * 8);
    }
    __syncthreads();
    // ---- stage-2: x_uai tile = xa @ uaiw^T (K=64) ----
    floatx4 acc2[2] = {};
#pragma unroll
    for (int kh = 0; kh < 2; kh++) {
      const int kc = kh * 4 + q;
      short8 a2 = *(const short8*)&xa[(wr * 16 + mlow) * 72 + kc * 8];
#pragma unroll
      for (int j = 0; j < 2; j++) {
        int orow = wc * 32 + j * 16 + mlow;
        short8 b2 = *(const short8*)&Bs[(orow * 8 + (kc ^ (orow & 7))) * 8];
        acc2[j] = __builtin_amdgcn_mfma_f32_16x16x32_bf16(a2, b2, acc2[j], 0, 0, 0);
      }
    }
#pragma unroll
    for (int rg = 0; rg < 4; rg++) {
      int row = r0 + wr * 16 + q * 4 + rg;
      float sqp = 0.f;
#pragma unroll
      for (int j = 0; j < 2; j++) {
        int o = wc * 32 + j * 16 + mlow;
        float v = acc2[j][rg] + aux1[o];
        Cb[(long long)z * bsC + (long long)row * ldc + o] = f2bf(v);
        sqp = fmaf(v, v, sqp);
      }
      sqp += __shfl_xor(sqp, 1);
      sqp += __shfl_xor(sqp, 2);
      sqp += __shfl_xor(sqp, 4);
      sqp += __shfl_xor(sqp, 8);
      if (mlow == 0) atomicAdd(&Zout[(long long)z * NI + row], sqp);
    }
  } else if constexpr (MODE == 5) {
    float ts = 0.f, tss = 0.f;
#pragma unroll
    for (int i = 0; i < MI; i++) {
#pragma unroll
      for (int j = 0; j < NJ; j++) {
#pragma unroll
        for (int rg = 0; rg < 4; rg++) {
          int r = r0 + wr * RM + i * 16 + q * 4 + rg;
          int ncol = n0 + wc * RN + j * 16 + mlow;
          float v = acc[i][j][rg];
          v += aux3[r] * aux1[(long long)z * NI + ncol] + aux4[r] * aux2[ncol];
          Cf[(long long)z * bsC + (long long)r * ldc + ncol] = v;
          ts += v;
          tss = fmaf(v, v, tss);
        }
      }
    }
    // block-level LN partial stats -> atomics; half = r-tile (rows 0-63 xn, 64-127 ft)
    float* red = (float*)As;  // 512 floats
    red[tid] = ts; red[256 + tid] = tss;
    __syncthreads();
    for (int st = 128; st > 0; st >>= 1) {
      if (tid < st) { red[tid] += red[tid + st]; red[256 + tid] += red[256 + tid + st]; }
      __syncthreads();
    }
    if (tid == 0) {
      const int half = r0 >> 6;
      atomicAdd(&Zout[z * 2 + half], red[0]);
      atomicAdd(&Zout[32 + z * 2 + half], red[256]);
    }
  } else {
    // MODE 4 / 6 element-wise epilogues
#pragma unroll
    for (int i = 0; i < MI; i++) {
#pragma unroll
      for (int j = 0; j < NJ; j++) {
#pragma unroll
        for (int rg = 0; rg < 4; rg++) {
          int r = r0 + wr * RM + i * 16 + q * 4 + rg;
          int ncol = n0 + wc * RN + j * 16 + mlow;
          float v = acc[i][j][rg];
          if constexpr (MODE == 4) {
            int blk = r >> 6, oo = r & 63;
            int drow = ((blk & 1) << 6) + oo;
            if (blk < 2) v = v / aux1[(long long)z * NI + ncol];  // fold 1/Zgl
            Cb[(long long)z * bsC + (long long)drow * 2048 + (long long)(blk >> 1) * 1024 + ncol] =
                f2bf(v);
          } else {
            Cb[(long long)z * bsC + (long long)r * ldc + ncol] = f2bf(v);
          }
        }
      }
    }
  }
}

// ---------------- lap_rowsum: dr[k][i] = rsqrt(1 + rowsum(graph[k][i])) --------------
__global__ __launch_bounds__(256) void lap_rowsum(const float* __restrict__ gd,
                                                  float* __restrict__ dr)
{
  const int ki = blockIdx.x;
  const float* row = gd + (long long)ki * NI;
  float s = 0.f;
  for (int j = threadIdx.x; j < NI; j += 256) s += row[j];
  __shared__ float red[256];
  red[threadIdx.x] = s; __syncthreads();
  for (int st = 128; st > 0; st >>= 1) {
    if (threadIdx.x < st) red[threadIdx.x] += red[threadIdx.x + st];
    __syncthreads();
  }
  if (threadIdx.x == 0) dr[ki] = rsqrtf(red[0] + 1.f);
}

// ---------------- mega_prep: blockIdx-range dispatch of all prep work ----------------
// [0,98)        small weights: stack4/rb2ext/rl2ext/uaiw_bf/attwT_bf/wcs
// [98,4194)     cast emb2_w -> bf16
// [4194,4450)   convT: h0aT[b][n][e] = lrelu(conv1d), transposed + vectorized
// [4450,8546)   g_direct (g2^T)
// [8546,9570)   g_trans (g1)
// [9570,10594)  cs1
__global__ __launch_bounds__(256) void mega_prep(
    const float* __restrict__ l1w, const float* __restrict__ l2w,
    const float* __restrict__ l2b, const float* __restrict__ uaiw,
    const float* __restrict__ attW,
    u16* __restrict__ stack4, float* __restrict__ rb2ext, float* __restrict__ rl2ext,
    u16* __restrict__ uaiw_bf, u16* __restrict__ attwT_bf, float* __restrict__ wcs,
    const float* __restrict__ emb2w, u16* __restrict__ emb2w_bf,
    const float* __restrict__ x, const float* __restrict__ ew,
    const float* __restrict__ eb, u16* __restrict__ h0aT,
    const float* __restrict__ gd, const float* __restrict__ dsum,
    u16* __restrict__ g2t, u16* __restrict__ g1,
    float* __restrict__ cs1)
{
  __shared__ float sm[1092];
  const int bid = blockIdx.x;
  const int t = threadIdx.x;
  if (bid < 98) {
    const int gid = bid * 256 + t;
    if (gid < 4096) {
      stack4[gid] = f2bf(l1w[gid]);
    } else if (gid < 8192) {
      stack4[gid] = f2bf(l2w[gid - 4096]);
    } else if (gid < 12288) {
      int tt = gid - 8192, o = tt >> 6, m = tt & 63;
      float s = 0.f;
      for (int c = 0; c < 64; c++) s = fmaf(l1w[o * 64 + c], l1w[c * 64 + m], s);
      stack4[gid] = f2bf(s);
    } else if (gid < 16384) {
      int tt = gid - 12288, o = tt >> 6, m = tt & 63;
      float s = 0.f;
      for (int c = 0; c < 64; c++) s = fmaf(l2w[o * 64 + c], l2w[c * 64 + m], s);
      stack4[gid] = f2bf(s);
    } else if (gid < 16512) {
      int r = gid - 16384;
      rb2ext[r] = (r < 64) ? 0.f : l2b[r - 64];
    } else if (gid < 16640) {
      int r = gid - 16512;
      float v = 0.f;
      if (r >= 64) { int o = r - 64; for (int c = 0; c < 64; c++) v = fmaf(l2w[o * 64 + c], l2b[c], v); }
      rl2ext[r] = v;
    } else if (gid < 20736) {
      uaiw_bf[gid - 16640] = f2bf(uaiw[gid - 16640]);
    } else if (gid < 24832) {
      int idx = gid - 20736;                 // attwT[c][e] = attW[e][c]
      int c = idx >> 6, e = idx & 63;
      attwT_bf[idx] = f2bf(attW[e * 64 + c]);
    } else if (gid < 24896) {
      int c = gid - 24832;                   // wcs[c] = sum_e attW[e][c]
      float s = 0.f;
      for (int e = 0; e < 64; e++) s += attW[e * 64 + c];
      wcs[c] = s;
    }
  } else if (bid < 4194) {
    const long long i = (long long)(bid - 98) * 256 + t;
    emb2w_bf[i] = f2bf(emb2w[i]);
  } else if (bid < 4450) {
    // convT: h0aT[b][n][e], 64 n per block, 4 threads/n each doing 16 e
    const int sub = bid - 4194;
    const int b = sub >> 4;
    const int nc = (sub & 15) * 64;
    float* we = sm;          // [64][16]
    float* be = sm + 1024;   // [64]
    for (int i = t; i < 1024; i += 256) we[i] = ew[i];
    if (t < 64) be[t] = eb[t];
    __syncthreads();
    const int n = nc + (t >> 2);
    const int e0 = (t & 3) * 16;
    const float* xb = x + (long long)b * CI * NI + n;
    float xv[16];
#pragma unroll
    for (int c = 0; c < CI; c++) xv[c] = xb[(long long)c * NI];
    u16 out16[16];
#pragma unroll
    for (int ee = 0; ee < 16; ee++) {
      const int e = e0 + ee;
      float a = be[e];
#pragma unroll
      for (int c = 0; c < CI; c++) a = fmaf(xv[c], we[e * 16 + c], a);
      out16[ee] = f2bf(lrelu01(a));
    }
    u16* dst = h0aT + (long long)b * S1 + (long long)n * 64 + e0;
    *(uint4*)dst = *(uint4*)out16;
    *(uint4*)(dst + 8) = *(uint4*)(out16 + 8);
  } else if (bid < 8546) {
    const long long idx = (long long)(bid - 4450) * 256 + t;
    const int m = (int)(idx >> 10), j = (int)(idx & 1023);
    const float* d = dsum + NI;
    float v = (gd[NN2 + idx] + (m == j ? 1.f : 0.f)) * d[m] * d[j];
    g2t[idx] = f2bf(v);
  } else if (bid < 9570) {
    const int sub = bid - 8546;
    const int bx = (sub & 31) * 32, by = (sub >> 5) * 32;
    const int lx = t & 31, ly = t >> 5;  // 32x8
    float* tile = sm;                    // 32x33
    for (int yy = ly; yy < 32; yy += 8)
      tile[yy * 33 + lx] = gd[(long long)(by + yy) * NI + bx + lx];
    __syncthreads();
    for (int yy = ly; yy < 32; yy += 8) {
      const int i = bx + yy, j = by + lx;
      float v = (tile[lx * 33 + yy] + (i == j ? 1.f : 0.f)) * dsum[i] * dsum[j];
      g1[(long long)i * NI + j] = f2bf(v);
    }
  } else {
    const int n = bid - 9570;
    float s = 0.f;
    for (int i = t; i < NI; i += 256) s = fmaf(gd[(long long)n * NI + i], dsum[i], s);
    float* red = sm;
    red[t] = s; __syncthreads();
    for (int st = 128; st > 0; st >>= 1) {
      if (t < st) red[t] += red[t + st];
      __syncthreads();
    }
    if (t == 0) cs1[n] = dsum[n] * (red[0] + dsum[n]);
  }
}

// cs2[m] = colsum g2; v2[m] = (cs1 @ g2)[m]
__global__ __launch_bounds__(256) void csv2_kernel(const float* __restrict__ gd1,
                                                   const float* __restrict__ d,
                                                   const float* __restrict__ cs1,
                                                   float* __restrict__ cs2,
                                                   float* __restrict__ v2)
{
  const int m = blockIdx.x;
  float s = 0.f, sv = 0.f;
  for (int n = threadIdx.x; n < NI; n += 256) {
    float g = gd1[(long long)m * NI + n] * d[n];
    s += g;
    sv = fmaf(g, cs1[n], sv);
  }
  __shared__ float r1[256], r2[256];
  r1[threadIdx.x] = s; r2[threadIdx.x] = sv; __syncthreads();
  for (int st = 128; st > 0; st >>= 1) {
    if (threadIdx.x < st) { r1[threadIdx.x] += r1[threadIdx.x + st]; r2[threadIdx.x] += r2[threadIdx.x + st]; }
    __syncthreads();
  }
  if (threadIdx.x == 0) {
    cs2[m] = d[m] * (r1[0] + d[m]);
    v2[m] = d[m] * (r2[0] + d[m] * cs1[m]);
  }
}

// cc[b][m] = sum_i W[b][m][i]/Zgl[b][i] + cs2[m]. One wave per row.
__global__ __launch_bounds__(256) void cc_kernel(const u16* __restrict__ W,
                                                 const float* __restrict__ Zgl,
                                                 const float* __restrict__ cs2,
                                                 float* __restrict__ cc)
{
  const int b = blockIdx.y;
  const int wid = threadIdx.x >> 6, lane = threadIdx.x & 63;
  const int m = blockIdx.x * 4 + wid;
  const u16* row = W + (long long)b * NN2 + (long long)m * NI;
  const float* zz = Zgl + (long long)b * NI;
  float s = 0.f;
#pragma unroll
  for (int it = 0; it < 4; it++) {
    const int j0 = it * 256 + lane * 4;
    uint2 pk = *(const uint2*)(row + j0);
    float4 zv = *(const float4*)(zz + j0);
    s += bf2f((u16)(pk.x & 0xffff)) / zv.x + bf2f((u16)(pk.x >> 16)) / zv.y
       + bf2f((u16)(pk.y & 0xffff)) / zv.z + bf2f((u16)(pk.y >> 16)) / zv.w;
  }
  for (int off = 1; off < 64; off <<= 1) s += __shfl_xor(s, off);
  if (lane == 0) cc[(long long)b * NI + m] = s + cs2[m];
}

// ---- LayerNorm apply + GELU + final gating, 64x64 tiles, LDS transpose of xu(bf16) ----
__global__ __launch_bounds__(256) void ln_final_t(const float* __restrict__ T,
                                                  const float* __restrict__ stats,
                                                  const float* __restrict__ lnw,
                                                  const float* __restrict__ lnb,
                                                  const float* __restrict__ ct,
                                                  const u16* __restrict__ xuT,
                                                  float* __restrict__ outp)
{
  __shared__ float xs[64 * 65];
  const int blk = blockIdx.x;
  const int b = blk >> 4;
  const int n0 = (blk & 15) << 6;
  const int t = threadIdx.x;
  const int tc = t & 63, tr = t >> 6;
#pragma unroll
  for (int i = 0; i < 16; i++) {
    int nn = i * 4 + tr;
    xs[tc * 65 + nn] = bf2f(xuT[((long long)b << 16) + (long long)(n0 + nn) * 64 + tc]);
  }
  __syncthreads();
  const float inv_n = 1.f / 65536.f;
  const float m0 = stats[b * 2] * inv_n;
  const float m1 = stats[b * 2 + 1] * inv_n;
  const float rs0 = rsqrtf(fmaxf(stats[32 + b * 2] * inv_n - m0 * m0, 0.f) + 1e-5f);
  const float rs1 = rsqrtf(fmaxf(stats[32 + b * 2 + 1] * inv_n - m1 * m1, 0.f) + 1e-5f);
#pragma unroll
  for (int j = 0; j < 16; j++) {
    const int c = j * 4 + tr;
    const int n = n0 + tc;
    const int rem = c * NI + n;
    const long long toff = (long long)b * S2 + rem;
    const float t0 = T[toff];
    const float t1 = T[toff + S1];
    const float w = lnw[rem], bb = lnb[rem];
    const float xn = (t0 - m0) * rs0 * w + bb;
    float ft = (t1 - m1) * rs1 * w + bb;
    ft = 0.5f * ft * (1.f + erff(ft * 0.70710678118654752f));
    const float u = xs[c * 65 + tc];
    const long long oidx = ((long long)b << 16) + rem;
    const float cn = fmaf(ft, ct[oidx] - xn, xn);
    const float el = cn > 0.f ? cn : expm1f(cn);
    outp[oidx] = fmaf(ft, el - u, u);
    outp[BCN + oidx] = cn;
  }
}

extern "C" void kernel_launch(void* const* d_in, const int* in_sizes, int n_in,
                              void* d_out, int out_size, void* d_ws, size_t ws_size,
                              hipStream_t stream)
{
  (void)in_sizes; (void)n_in; (void)out_size; (void)ws_size;
  const float* x      = (const float*)d_in[0];
  const float* ct     = (const float*)d_in[1];
  const float* gdata  = (const float*)d_in[2];
  const float* emb_w  = (const float*)d_in[3];
  const float* emb_b  = (const float*)d_in[4];
  const float* emb2_w = (const float*)d_in[5];
  const float* emb2_b = (const float*)d_in[6];
  const float* att_W  = (const float*)d_in[7];
  const float* att_a  = (const float*)d_in[8];
  // d_in[9] att_GL unused: softmax(relu(GL GL^T)) > 0 everywhere -> mask is a no-op
  const float* uai_w  = (const float*)d_in[10];
  const float* uai_b  = (const float*)d_in[11];
  const float* lin1_w = (const float*)d_in[12];
  const float* lin2_w = (const float*)d_in[13];
  const float* lin2_b = (const float*)d_in[14];
  const float* ln_w   = (const float*)d_in[15];
  const float* ln_b   = (const float*)d_in[16];
  float* outp = (float*)d_out;

  float* ws = (float*)d_ws;
  long long o = 0;
  auto af = [&](long long n) { float* p = ws + o; o += (n + 63) & ~63LL; return p; };
  auto au = [&](long long n) { return (u16*)af((n + 1) / 2); };

  float* Tacc    = af(S2 * BATCH);
  float* s1      = af(BNv);
  float* s2      = af(BNv);
  float* dsum    = af(2 * NI);
  float* cs1v    = af(NI);
  float* cs2v    = af(NI);
  float* v2v     = af(NI);
  float* ccv     = af(BNv);
  float* rb2ext  = af(128);
  float* rl2ext  = af(128);
  float* wcs     = af(64);
  // contiguous zero-init region: Zgl, sqv, stats(64), s2mU(16)
  float* zeroreg = af(2 * BNv + 80);
  float* Zgl     = zeroreg;
  float* sqv     = zeroreg + BNv;
  float* stats   = zeroreg + 2 * BNv;
  unsigned* s2mU = (unsigned*)(stats + 64);
  u16* emb2w_bf  = au(NN2);
  u16* h0aTb     = au(S1 * BATCH);   // [b][n][e]
  u16* ybf       = au(S1 * BATCH);   // y = attW^T @ h0a, [b][c][n]
  u16* hTb       = au(S1 * BATCH);   // [b][c][n]
  u16* xuaiTb    = au(S1 * BATCH);   // [b][n][c]
  u16* g1b       = au(NN2);
  u16* g2tb      = au(NN2);
  u16* G12b      = au(NN2);
  u16* Abig      = au((long long)BATCH * 128 * 2048);
  u16* stack4    = au(256 * 64);
  u16* uaiw_bf   = au(CE * CE);
  u16* attwT_bf  = au(CE * CE);
  u16* bigW      = au(BNN);  // 32 MB: gram W (att-p computed on the fly)

  hipMemsetAsync(zeroreg, 0, (2 * BNv + 80) * sizeof(float), stream);

  lap_rowsum<<<2 * NI, 256, 0, stream>>>(gdata, dsum);

  mega_prep<<<10594, 256, 0, stream>>>(
      lin1_w, lin2_w, lin2_b, uai_w, att_W,
      stack4, rb2ext, rl2ext, uaiw_bf, attwT_bf, wcs,
      emb2_w, emb2w_bf, x, emb_w, emb_b, h0aTb,
      gdata, dsum, g2tb, g1b, cs1v);

  csv2_kernel<<<NI, 256, 0, stream>>>(gdata + NN2, dsum + NI, cs1v, cs2v, v2v);

  // G12t = (g1@g2)^T = TN(A=g2t, Bt=g1); BM=32 -> 512 blocks = 2/CU
  mgemm<32, 64, 6><<<dim3(16, 32, 1), 256, 0, stream>>>(
      g2tb, g1b, nullptr, NI, NI, NI, NI, 0, 0,
      nullptr, G12b, NI, 0, nullptr, nullptr, nullptr, nullptr, nullptr);

  // y[b][c][n] = attW^T @ h0a  (K=64, tiny)
  mgemm<64, 64, 6><<<dim3(16, 1, BATCH), 256, 0, stream>>>(
      attwT_bf, h0aTb, nullptr, CE, CE, CE, CE, 0, S1,
      nullptr, ybf, NI, S1, nullptr, nullptr, nullptr, nullptr, nullptr);

  // hT[b][c][n'] = y @ emb2w^T + wcs (x) emb2_b; epilogue computes s1/s2/s2max
  // (replaces the old h0T K=1024 GEMM + hT GEMM); BN=32 -> 512 blocks = 2/CU
  mgemm<64, 32, 14><<<dim3(32, 1, BATCH), 256, 0, stream>>>(
      ybf, emb2w_bf, (const u16*)s2mU, NI, NI, NI, NI, S1, 0,
      s1, hTb, NI, S1, emb2_b, att_a, wcs, nullptr, s2);

  // fused two-stage: x_att = relu((p@h)/Z) then x_uai = x_att @ uaiw^T + uai_b
  mgemm<32, 64, 13><<<dim3(1, 32, BATCH), 256, 0, stream>>>(
      hTb, hTb, uaiw_bf, NI, NI, NI, NI, 0, S1,
      nullptr, xuaiTb, CE, S1, uai_b, s1, s2, (const float*)s2mU, sqv);

  // gram/gl weights (128x128 tiles; exp epilogue; rowsums into Zgl)
  mgemm<128, 128, 3><<<dim3(8, 8, BATCH), 256, 0, stream>>>(
      xuaiTb, xuaiTb, nullptr, CE, CE, CE, CE, S1, S1,
      nullptr, bigW, NI, NN2, sqv, nullptr, nullptr, nullptr, Zgl);

  cc_kernel<<<dim3(NI / 4, BATCH), 256, 0, stream>>>(bigW, Zgl, cs2v, ccv);

  // Abig = [[L1u/Z | L1L1u],[L2u/Z | L2L2u]] bf16
  mgemm<64, 64, 4><<<dim3(16, 4, BATCH), 256, 0, stream>>>(
      stack4, xuaiTb, nullptr, CE, CE, CE, CE, 0, S1,
      nullptr, Abig, 0, (long long)128 * 2048, Zgl, nullptr, nullptr, nullptr, nullptr);

  // fused: Tacc = Abig @ [W ; G12t] + b2 (x) cc + (L2 b2) (x) v2, + LN-stats atomics
  mgemm<64, 64, 5><<<dim3(16, 2, BATCH), 256, 0, stream>>>(
      Abig, bigW, G12b, NI, 2 * NI, 2048, NI, (long long)128 * 2048, NN2,
      Tacc, nullptr, NI, S2, ccv, v2v, rb2ext, rl2ext, stats);

  ln_final_t<<<256, 256, 0, stream>>>(Tacc, stats, ln_w, ln_b, ct, xuaiTb, outp);
}

// Round 11
// 243.188 us; speedup vs baseline: 1.0664x; 1.0664x over previous
//
#include <hip/hip_runtime.h>
#include <math.h>

typedef unsigned short u16;
typedef __attribute__((ext_vector_type(8))) short short8;
typedef __attribute__((ext_vector_type(4))) float floatx4;

constexpr int BATCH = 16;
constexpr int NI = 1024;
constexpr int CE = 64;
constexpr int CI = 16;
constexpr long long NN2  = (long long)NI * NI;          // 1M
constexpr long long BCN  = (long long)BATCH * CE * NI;  // 1M
constexpr long long BNv  = (long long)BATCH * NI;       // 16K
constexpr long long BNN  = (long long)BATCH * NI * NI;  // 16M
constexpr long long S1 = (long long)CE * NI;            // 65536
constexpr long long S2 = 2 * S1;                        // 131072
constexpr int ZERON = (int)(2 * BNv + 80);              // zero-init region elements

__device__ __forceinline__ float lrelu01(float x) { return x > 0.f ? x : 0.01f * x; }

__device__ __forceinline__ u16 f2bf(float f) {
  unsigned u = __builtin_bit_cast(unsigned, f);
  return (u16)((u + 0x7fffu + ((u >> 16) & 1u)) >> 16);  // RNE
}
__device__ __forceinline__ float bf2f(u16 h) {
  unsigned u = ((unsigned)h) << 16;
  return __builtin_bit_cast(float, u);
}
// monotonic uint key for float atomicMax (zero-init safe: real-float keys > 0)
__device__ __forceinline__ unsigned fkey(float f) {
  unsigned u = __builtin_bit_cast(unsigned, f);
  return (u & 0x80000000u) ? ~u : (u | 0x80000000u);
}
__device__ __forceinline__ float funkey(unsigned k) {
  unsigned u = (k & 0x80000000u) ? (k & 0x7fffffffu) : ~k;
  return __builtin_bit_cast(float, u);
}

// ================= MFMA TN GEMM: C[r][m] = sum_k A[r][k] * Bt[m][k] ==============
// A, Bt bf16 row-major K-contiguous. BK=64, XOR-swizzled 16B chunks in LDS.
// 4 waves 2x2; wave tile (BM/2)x(BN/2); 16x16x32 MFMAs.
// MODE: 3 gram exp + rowsum | 4 Abig scatter w/ bias-fold + Z-div |
//       5 dual-B + cs2/v2 rank-1 + LN-stats + bf16 out | 6 plain bf16 |
//       13 A = attention-p on the fly + in-block invZ + relu + second MFMA stage |
//       14 hT direct: +rank-1 (wcs x emb2_b) + per-column s1/s2 dots + s2max |
//       15 flattened grid: blocks <512 = G12 GEMM (plain bf16), >=512 = csv2 rows
template<int BM, int BN, int MODE>
__global__ __launch_bounds__(256) void mgemm(
    const u16* __restrict__ Ag, const u16* __restrict__ B1g, const u16* __restrict__ B2g,
    int K1, int K, int lda, int ldb, long long bsA, long long bsB1,
    float* __restrict__ Cf, u16* __restrict__ Cb, int ldc, long long bsC,
    const float* __restrict__ aux1, const float* __restrict__ aux2,
    const float* __restrict__ aux3, const float* __restrict__ aux4,
    float* __restrict__ Zout)
{
  constexpr int RM = BM / 2, RN = BN / 2, MI = RM / 16, NJ = RN / 16;
  __shared__ __align__(16) u16 As[BM * 64];
  __shared__ __align__(16) u16 Bs[BN * 64];
  __shared__ __align__(16) u16 xa[MODE == 13 ? 32 * 72 : 1];  // stage-2 A tile (padded)
  const int tid = threadIdx.x;
  int z, n0, r0;
  if constexpr (MODE == 15) {
    const int id = blockIdx.x;
    if (id >= 512) {
      // csv2: cs2[m]=colsum g2; v2[m]=(cs1@g2)[m].  aux3=gdata1, aux2=d, aux1=cs1
      const int m = id - 512;
      float s = 0.f, sv = 0.f;
      for (int n = tid; n < NI; n += 256) {
        float g = aux3[(long long)m * NI + n] * aux2[n];
        s += g;
        sv = fmaf(g, aux1[n], sv);
      }
      float* r1 = (float*)As;
      float* r2 = (float*)As + 256;
      r1[tid] = s; r2[tid] = sv; __syncthreads();
      for (int st = 128; st > 0; st >>= 1) {
        if (tid < st) { r1[tid] += r1[tid + st]; r2[tid] += r2[tid + st]; }
        __syncthreads();
      }
      if (tid == 0) {
        float dm = aux2[m];
        Cf[m] = dm * (r1[0] + dm);
        Zout[m] = dm * (r2[0] + dm * aux1[m]);
      }
      return;
    }
    z = 0; n0 = (id & 15) * BN; r0 = (id >> 4) * BM;
  } else {
    z = blockIdx.z; n0 = blockIdx.x * BN; r0 = blockIdx.y * BM;
  }
  const u16* Ab = Ag + (long long)z * bsA + (long long)r0 * lda;
  const u16* Bb1 = B1g + (long long)z * bsB1 + (long long)n0 * ldb;
  const int lane = tid & 63;
  const int wid = tid >> 6;
  const int wr = wid >> 1, wc = wid & 1;
  const int q = lane >> 4, mlow = lane & 15;

  floatx4 acc[MI][NJ] = {};
  float zp[(BM * 8) / 256] = {};       // MODE13 row p-sums

  for (int k0 = 0; k0 < K; k0 += 64) {
    if constexpr (MODE == 13) {
      // A-tile = attention p from s1 (aux2), s2 (aux3), s2max key (aux4)
      const float* s1z = aux2 + (long long)z * NI;
      const float* s2z = aux3 + (long long)z * NI;
      const float mb = funkey(((const unsigned*)aux4)[z]);
#pragma unroll
      for (int s = 0; s < (BM * 8) / 256; s++) {
        int cid = tid + s * 256;
        int r = cid >> 3, craw = cid & 7;
        float s1r = s1z[r0 + r];
        float mr = lrelu01(s1r + mb);
        const float* sp = s2z + k0 + craw * 8;
        float4 sa = *(const float4*)sp;
        float4 sb = *(const float4*)(sp + 4);
        float p0 = __expf(lrelu01(s1r + sa.x) - mr);
        float p1 = __expf(lrelu01(s1r + sa.y) - mr);
        float p2 = __expf(lrelu01(s1r + sa.z) - mr);
        float p3 = __expf(lrelu01(s1r + sa.w) - mr);
        float p4 = __expf(lrelu01(s1r + sb.x) - mr);
        float p5 = __expf(lrelu01(s1r + sb.y) - mr);
        float p6 = __expf(lrelu01(s1r + sb.z) - mr);
        float p7 = __expf(lrelu01(s1r + sb.w) - mr);
        zp[s] += p0 + p1 + p2 + p3 + p4 + p5 + p6 + p7;
        uint4 v;
        v.x = (unsigned)f2bf(p0) | ((unsigned)f2bf(p1) << 16);
        v.y = (unsigned)f2bf(p2) | ((unsigned)f2bf(p3) << 16);
        v.z = (unsigned)f2bf(p4) | ((unsigned)f2bf(p5) << 16);
        v.w = (unsigned)f2bf(p6) | ((unsigned)f2bf(p7) << 16);
        *(uint4*)&As[(r * 8 + (craw ^ (r & 7))) * 8] = v;
      }
    } else {
      const u16* Asrc = Ab + k0;
#pragma unroll
      for (int s = 0; s < (BM * 8) / 256; s++) {
        int cid = tid + s * 256;
        int r = cid >> 3, craw = cid & 7;
        uint4 v = *(const uint4*)(Asrc + (long long)r * lda + craw * 8);
        *(uint4*)&As[(r * 8 + (craw ^ (r & 7))) * 8] = v;
      }
    }
    {
      const u16* Bsrc = (k0 < K1) ? (Bb1 + k0)
                                  : (B2g + (long long)n0 * ldb + (k0 - K1));
#pragma unroll
      for (int s = 0; s < (BN * 8) / 256; s++) {
        int cid = tid + s * 256;
        int r = cid >> 3, craw = cid & 7;
        uint4 v = *(const uint4*)(Bsrc + (long long)r * ldb + craw * 8);
        *(uint4*)&Bs[(r * 8 + (craw ^ (r & 7))) * 8] = v;
      }
    }
    __syncthreads();
#pragma unroll
    for (int kh = 0; kh < 2; kh++) {
      const int kc = kh * 4 + q;
      short8 afr[MI], bfr[NJ];
#pragma unroll
      for (int i = 0; i < MI; i++) {
        int row = wr * RM + i * 16 + mlow;
        afr[i] = *(const short8*)&As[(row * 8 + (kc ^ (row & 7))) * 8];
      }
#pragma unroll
      for (int j = 0; j < NJ; j++) {
        int row = wc * RN + j * 16 + mlow;
        bfr[j] = *(const short8*)&Bs[(row * 8 + (kc ^ (row & 7))) * 8];
      }
#pragma unroll
      for (int i = 0; i < MI; i++)
#pragma unroll
        for (int j = 0; j < NJ; j++)
          acc[i][j] = __builtin_amdgcn_mfma_f32_16x16x32_bf16(afr[i], bfr[j], acc[i][j], 0, 0, 0);
    }
    __syncthreads();
  }

  if constexpr (MODE == 3) {
    const float* sqb = aux1 + (long long)z * NI;
#pragma unroll
    for (int i = 0; i < MI; i++) {
#pragma unroll
      for (int rg = 0; rg < 4; rg++) {
        int r = r0 + wr * RM + i * 16 + q * 4 + rg;
        float sqi = sqb[r];
        float rsum = 0.f;
#pragma unroll
        for (int j = 0; j < NJ; j++) {
          int ncol = n0 + wc * RN + j * 16 + mlow;
          float d2 = fmaxf(sqi + sqb[ncol] - 2.f * acc[i][j][rg], 0.f);
          float w = __expf(__expf(-d2 * (1.f / 128.f)) + (r == ncol ? 1.f : 0.f) - 2.f);
          Cb[(long long)z * bsC + (long long)r * ldc + ncol] = f2bf(w);
          rsum += w;
        }
        rsum += __shfl_xor(rsum, 1);
        rsum += __shfl_xor(rsum, 2);
        rsum += __shfl_xor(rsum, 4);
        rsum += __shfl_xor(rsum, 8);
        if (mlow == 0) atomicAdd(&Zout[(long long)z * NI + r], rsum);
      }
    }
  } else if constexpr (MODE == 14) {
    // hT write + rank-1 bias (wcs=aux3 x emb2_b=aux1) + column dots w/ atta (aux2)
    float ps1 = 0.f, ps2 = 0.f;
#pragma unroll
    for (int i = 0; i < MI; i++) {
#pragma unroll
      for (int rg = 0; rg < 4; rg++) {
        int r = wr * RM + i * 16 + q * 4 + rg;  // r0 == 0 (grid.y == 1)
        int ncol = n0 + wc * RN + mlow;
        float v = acc[i][0][rg] + aux3[r] * aux1[ncol];
        Cb[(long long)z * bsC + (long long)r * ldc + ncol] = f2bf(v);
        ps1 = fmaf(v, aux2[r], ps1);
        ps2 = fmaf(v, aux2[64 + r], ps2);
      }
    }
    ps1 += __shfl_xor(ps1, 16); ps1 += __shfl_xor(ps1, 32);
    ps2 += __shfl_xor(ps2, 16); ps2 += __shfl_xor(ps2, 32);
    float* sred = (float*)As;  // s1: [32 cols][2 wr]; s2 at +64
    const int col = wc * RN + mlow;
    if (q == 0) { sred[col * 2 + wr] = ps1; sred[64 + col * 2 + wr] = ps2; }
    __syncthreads();
    if (tid < 32) {
      float v1 = sred[tid * 2] + sred[tid * 2 + 1];
      float v2 = sred[64 + tid * 2] + sred[64 + tid * 2 + 1];
      Cf[(long long)z * NI + n0 + tid] = v1;
      Zout[(long long)z * NI + n0 + tid] = v2;
      float mx = v2;
      for (int off = 1; off < 32; off <<= 1) mx = fmaxf(mx, __shfl_xor(mx, off));
      if (tid == 0) atomicMax((unsigned*)B2g + z, fkey(mx));
    }
  } else if constexpr (MODE == 13) {
    // ---- stage-1 finish: in-block softmax denominator (BM=32) ----
    float* zred = (float*)xa;            // [32][8]
    float* zinv = (float*)xa + 256;      // [32]
    zred[(tid >> 3) * 8 + (tid & 7)] = zp[0];
    __syncthreads();
    if (tid < 32) {
      float sum = 0.f;
#pragma unroll
      for (int j = 0; j < 8; j++) sum += zred[tid * 8 + j];
      zinv[tid] = 1.f / sum;
    }
    __syncthreads();
    float zr[4];
#pragma unroll
    for (int rg = 0; rg < 4; rg++) zr[rg] = zinv[wr * 16 + q * 4 + rg];
    __syncthreads();  // all zinv reads done before xa overwrite
    // ---- x_att tile (relu, scaled) -> xa as A-fragments; uaiw -> Bs ----
#pragma unroll
    for (int j = 0; j < NJ; j++) {
#pragma unroll
      for (int rg = 0; rg < 4; rg++) {
        int row = wr * 16 + q * 4 + rg;
        int col = wc * RN + j * 16 + mlow;
        float v = fmaxf(acc[0][j][rg] * zr[rg], 0.f);
        xa[row * 72 + col] = f2bf(v);
      }
    }
#pragma unroll
    for (int s = 0; s < 2; s++) {
      int cid = tid + s * 256;
      int r = cid >> 3, craw = cid & 7;
      *(uint4*)&Bs[(r * 8 + (craw ^ (r & 7))) * 8] =
          *(const uint4*)(B2g + r * 64 + craw * 8);
    }
    __syncthreads();
    // ---- stage-2: x_uai tile = xa @ uaiw^T (K=64) ----
    floatx4 acc2[2] = {};
#pragma unroll
    for (int kh = 0; kh < 2; kh++) {
      const int kc = kh * 4 + q;
      short8 a2 = *(const short8*)&xa[(wr * 16 + mlow) * 72 + kc * 8];
#pragma unroll
      for (int j = 0; j < 2; j++) {
        int orow = wc * 32 + j * 16 + mlow;
        short8 b2 = *(const short8*)&Bs[(orow * 8 + (kc ^ (orow & 7))) * 8];
        acc2[j] = __builtin_amdgcn_mfma_f32_16x16x32_bf16(a2, b2, acc2[j], 0, 0, 0);
      }
    }
#pragma unroll
    for (int rg = 0; rg < 4; rg++) {
      int row = r0 + wr * 16 + q * 4 + rg;
      float sqp = 0.f;
#pragma unroll
      for (int j = 0; j < 2; j++) {
        int o = wc * 32 + j * 16 + mlow;
        float v = acc2[j][rg] + aux1[o];
        Cb[(long long)z * bsC + (long long)row * ldc + o] = f2bf(v);
        sqp = fmaf(v, v, sqp);
      }
      sqp += __shfl_xor(sqp, 1);
      sqp += __shfl_xor(sqp, 2);
      sqp += __shfl_xor(sqp, 4);
      sqp += __shfl_xor(sqp, 8);
      if (mlow == 0) atomicAdd(&Zout[(long long)z * NI + row], sqp);
    }
  } else if constexpr (MODE == 5) {
    // rank-1: rb2ext (aux3) x cs2 (aux1) + rl2ext (aux4) x v2 (aux2); bf16 out;
    // LN stats from fp32 values
    float ts = 0.f, tss = 0.f;
#pragma unroll
    for (int i = 0; i < MI; i++) {
#pragma unroll
      for (int j = 0; j < NJ; j++) {
#pragma unroll
        for (int rg = 0; rg < 4; rg++) {
          int r = r0 + wr * RM + i * 16 + q * 4 + rg;
          int ncol = n0 + wc * RN + j * 16 + mlow;
          float v = acc[i][j][rg];
          v += aux3[r] * aux1[ncol] + aux4[r] * aux2[ncol];
          Cb[(long long)z * bsC + (long long)r * ldc + ncol] = f2bf(v);
          ts += v;
          tss = fmaf(v, v, tss);
        }
      }
    }
    // block-level LN partial stats -> atomics; half = r-tile (rows 0-63 xn, 64-127 ft)
    float* red = (float*)As;  // 512 floats
    red[tid] = ts; red[256 + tid] = tss;
    __syncthreads();
    for (int st = 128; st > 0; st >>= 1) {
      if (tid < st) { red[tid] += red[tid + st]; red[256 + tid] += red[256 + tid + st]; }
      __syncthreads();
    }
    if (tid == 0) {
      const int half = r0 >> 6;
      atomicAdd(&Zout[z * 2 + half], red[0]);
      atomicAdd(&Zout[32 + z * 2 + half], red[256]);
    }
  } else {
    // MODE 4 / 6 / 15(GEMM half) element-wise epilogues
#pragma unroll
    for (int i = 0; i < MI; i++) {
#pragma unroll
      for (int j = 0; j < NJ; j++) {
#pragma unroll
        for (int rg = 0; rg < 4; rg++) {
          int r = r0 + wr * RM + i * 16 + q * 4 + rg;
          int ncol = n0 + wc * RN + j * 16 + mlow;
          float v = acc[i][j][rg];
          if constexpr (MODE == 4) {
            int blk = r >> 6, oo = r & 63;
            int drow = ((blk & 1) << 6) + oo;
            // bias-fold: Z-scaled halves get +rb2ext BEFORE /Zgl -> l2 bias's
            // cc-contribution flows through the W product (cc_kernel eliminated)
            if (blk < 2) v = (v + aux3[drow]) / aux1[(long long)z * NI + ncol];
            Cb[(long long)z * bsC + (long long)drow * 2048 + (long long)(blk >> 1) * 1024 + ncol] =
                f2bf(v);
          } else {
            Cb[(long long)z * bsC + (long long)r * ldc + ncol] = f2bf(v);
          }
        }
      }
    }
  }
}

// ---- lap_rowsum + zero-init: blocks <2048 do dr[k][i]; rest zero the atomic region ----
__global__ __launch_bounds__(256) void lap_rowsum(const float* __restrict__ gd,
                                                  float* __restrict__ dr,
                                                  float* __restrict__ zero)
{
  if (blockIdx.x >= 2048) {
    int i = (blockIdx.x - 2048) * 256 + threadIdx.x;
    if (i < ZERON) zero[i] = 0.f;
    return;
  }
  const int ki = blockIdx.x;
  const float* row = gd + (long long)ki * NI;
  float s = 0.f;
  for (int j = threadIdx.x; j < NI; j += 256) s += row[j];
  __shared__ float red[256];
  red[threadIdx.x] = s; __syncthreads();
  for (int st = 128; st > 0; st >>= 1) {
    if (threadIdx.x < st) red[threadIdx.x] += red[threadIdx.x + st];
    __syncthreads();
  }
  if (threadIdx.x == 0) dr[ki] = rsqrtf(red[0] + 1.f);
}

// ---------------- mega_prep: blockIdx-range dispatch of all prep work ----------------
// [0,98)        small weights: stack4/rb2ext/rl2ext/uaiw_bf/attwT_bf/wcs
// [98,4194)     cast emb2_w -> bf16
// [4194,4450)   convT: h0aT[b][n][e] = lrelu(conv1d), transposed + vectorized
// [4450,8546)   g_direct (g2^T)
// [8546,9570)   g_trans (g1)
// [9570,10594)  cs1
__global__ __launch_bounds__(256) void mega_prep(
    const float* __restrict__ l1w, const float* __restrict__ l2w,
    const float* __restrict__ l2b, const float* __restrict__ uaiw,
    const float* __restrict__ attW,
    u16* __restrict__ stack4, float* __restrict__ rb2ext, float* __restrict__ rl2ext,
    u16* __restrict__ uaiw_bf, u16* __restrict__ attwT_bf, float* __restrict__ wcs,
    const float* __restrict__ emb2w, u16* __restrict__ emb2w_bf,
    const float* __restrict__ x, const float* __restrict__ ew,
    const float* __restrict__ eb, u16* __restrict__ h0aT,
    const float* __restrict__ gd, const float* __restrict__ dsum,
    u16* __restrict__ g2t, u16* __restrict__ g1,
    float* __restrict__ cs1)
{
  __shared__ float sm[1092];
  const int bid = blockIdx.x;
  const int t = threadIdx.x;
  if (bid < 98) {
    const int gid = bid * 256 + t;
    if (gid < 4096) {
      stack4[gid] = f2bf(l1w[gid]);
    } else if (gid < 8192) {
      stack4[gid] = f2bf(l2w[gid - 4096]);
    } else if (gid < 12288) {
      int tt = gid - 8192, o = tt >> 6, m = tt & 63;
      float s = 0.f;
      for (int c = 0; c < 64; c++) s = fmaf(l1w[o * 64 + c], l1w[c * 64 + m], s);
      stack4[gid] = f2bf(s);
    } else if (gid < 16384) {
      int tt = gid - 12288, o = tt >> 6, m = tt & 63;
      float s = 0.f;
      for (int c = 0; c < 64; c++) s = fmaf(l2w[o * 64 + c], l2w[c * 64 + m], s);
      stack4[gid] = f2bf(s);
    } else if (gid < 16512) {
      int r = gid - 16384;
      rb2ext[r] = (r < 64) ? 0.f : l2b[r - 64];
    } else if (gid < 16640) {
      int r = gid - 16512;
      float v = 0.f;
      if (r >= 64) { int o = r - 64; for (int c = 0; c < 64; c++) v = fmaf(l2w[o * 64 + c], l2b[c], v); }
      rl2ext[r] = v;
    } else if (gid < 20736) {
      uaiw_bf[gid - 16640] = f2bf(uaiw[gid - 16640]);
    } else if (gid < 24832) {
      int idx = gid - 20736;                 // attwT[c][e] = attW[e][c]
      int c = idx >> 6, e = idx & 63;
      attwT_bf[idx] = f2bf(attW[e * 64 + c]);
    } else if (gid < 24896) {
      int c = gid - 24832;                   // wcs[c] = sum_e attW[e][c]
      float s = 0.f;
      for (int e = 0; e < 64; e++) s += attW[e * 64 + c];
      wcs[c] = s;
    }
  } else if (bid < 4194) {
    const long long i = (long long)(bid - 98) * 256 + t;
    emb2w_bf[i] = f2bf(emb2w[i]);
  } else if (bid < 4450) {
    // convT: h0aT[b][n][e], 64 n per block, 4 threads/n each doing 16 e
    const int sub = bid - 4194;
    const int b = sub >> 4;
    const int nc = (sub & 15) * 64;
    float* we = sm;          // [64][16]
    float* be = sm + 1024;   // [64]
    for (int i = t; i < 1024; i += 256) we[i] = ew[i];
    if (t < 64) be[t] = eb[t];
    __syncthreads();
    const int n = nc + (t >> 2);
    const int e0 = (t & 3) * 16;
    const float* xb = x + (long long)b * CI * NI + n;
    float xv[16];
#pragma unroll
    for (int c = 0; c < CI; c++) xv[c] = xb[(long long)c * NI];
    u16 out16[16];
#pragma unroll
    for (int ee = 0; ee < 16; ee++) {
      const int e = e0 + ee;
      float a = be[e];
#pragma unroll
      for (int c = 0; c < CI; c++) a = fmaf(xv[c], we[e * 16 + c], a);
      out16[ee] = f2bf(lrelu01(a));
    }
    u16* dst = h0aT + (long long)b * S1 + (long long)n * 64 + e0;
    *(uint4*)dst = *(uint4*)out16;
    *(uint4*)(dst + 8) = *(uint4*)(out16 + 8);
  } else if (bid < 8546) {
    const long long idx = (long long)(bid - 4450) * 256 + t;
    const int m = (int)(idx >> 10), j = (int)(idx & 1023);
    const float* d = dsum + NI;
    float v = (gd[NN2 + idx] + (m == j ? 1.f : 0.f)) * d[m] * d[j];
    g2t[idx] = f2bf(v);
  } else if (bid < 9570) {
    const int sub = bid - 8546;
    const int bx = (sub & 31) * 32, by = (sub >> 5) * 32;
    const int lx = t & 31, ly = t >> 5;  // 32x8
    float* tile = sm;                    // 32x33
    for (int yy = ly; yy < 32; yy += 8)
      tile[yy * 33 + lx] = gd[(long long)(by + yy) * NI + bx + lx];
    __syncthreads();
    for (int yy = ly; yy < 32; yy += 8) {
      const int i = bx + yy, j = by + lx;
      float v = (tile[lx * 33 + yy] + (i == j ? 1.f : 0.f)) * dsum[i] * dsum[j];
      g1[(long long)i * NI + j] = f2bf(v);
    }
  } else {
    const int n = bid - 9570;
    float s = 0.f;
    for (int i = t; i < NI; i += 256) s = fmaf(gd[(long long)n * NI + i], dsum[i], s);
    float* red = sm;
    red[t] = s; __syncthreads();
    for (int st = 128; st > 0; st >>= 1) {
      if (t < st) red[t] += red[t + st];
      __syncthreads();
    }
    if (t == 0) cs1[n] = dsum[n] * (red[0] + dsum[n]);
  }
}

// ---- LayerNorm apply + GELU + final gating; Tacc in bf16; LDS transpose of xu ----
__global__ __launch_bounds__(256) void ln_final_t(const u16* __restrict__ T,
                                                  const float* __restrict__ stats,
                                                  const float* __restrict__ lnw,
                                                  const float* __restrict__ lnb,
                                                  const float* __restrict__ ct,
                                                  const u16* __restrict__ xuT,
                                                  float* __restrict__ outp)
{
  __shared__ float xs[64 * 65];
  const int blk = blockIdx.x;
  const int b = blk >> 4;
  const int n0 = (blk & 15) << 6;
  const int t = threadIdx.x;
  const int tc = t & 63, tr = t >> 6;
#pragma unroll
  for (int i = 0; i < 16; i++) {
    int nn = i * 4 + tr;
    xs[tc * 65 + nn] = bf2f(xuT[((long long)b << 16) + (long long)(n0 + nn) * 64 + tc]);
  }
  __syncthreads();
  const float inv_n = 1.f / 65536.f;
  const float m0 = stats[b * 2] * inv_n;
  const float m1 = stats[b * 2 + 1] * inv_n;
  const float rs0 = rsqrtf(fmaxf(stats[32 + b * 2] * inv_n - m0 * m0, 0.f) + 1e-5f);
  const float rs1 = rsqrtf(fmaxf(stats[32 + b * 2 + 1] * inv_n - m1 * m1, 0.f) + 1e-5f);
#pragma unroll
  for (int j = 0; j < 16; j++) {
    const int c = j * 4 + tr;
    const int n = n0 + tc;
    const int rem = c * NI + n;
    const long long toff = (long long)b * S2 + rem;
    const float t0 = bf2f(T[toff]);
    const float t1 = bf2f(T[toff + S1]);
    const float w = lnw[rem], bb = lnb[rem];
    const float xn = (t0 - m0) * rs0 * w + bb;
    float ft = (t1 - m1) * rs1 * w + bb;
    ft = 0.5f * ft * (1.f + erff(ft * 0.70710678118654752f));
    const float u = xs[c * 65 + tc];
    const long long oidx = ((long long)b << 16) + rem;
    const float cn = fmaf(ft, ct[oidx] - xn, xn);
    const float el = cn > 0.f ? cn : expm1f(cn);
    outp[oidx] = fmaf(ft, el - u, u);
    outp[BCN + oidx] = cn;
  }
}

extern "C" void kernel_launch(void* const* d_in, const int* in_sizes, int n_in,
                              void* d_out, int out_size, void* d_ws, size_t ws_size,
                              hipStream_t stream)
{
  (void)in_sizes; (void)n_in; (void)out_size; (void)ws_size;
  const float* x      = (const float*)d_in[0];
  const float* ct     = (const float*)d_in[1];
  const float* gdata  = (const float*)d_in[2];
  const float* emb_w  = (const float*)d_in[3];
  const float* emb_b  = (const float*)d_in[4];
  const float* emb2_w = (const float*)d_in[5];
  const float* emb2_b = (const float*)d_in[6];
  const float* att_W  = (const float*)d_in[7];
  const float* att_a  = (const float*)d_in[8];
  // d_in[9] att_GL unused: softmax(relu(GL GL^T)) > 0 everywhere -> mask is a no-op
  const float* uai_w  = (const float*)d_in[10];
  const float* uai_b  = (const float*)d_in[11];
  const float* lin1_w = (const float*)d_in[12];
  const float* lin2_w = (const float*)d_in[13];
  const float* lin2_b = (const float*)d_in[14];
  const float* ln_w   = (const float*)d_in[15];
  const float* ln_b   = (const float*)d_in[16];
  float* outp = (float*)d_out;

  float* ws = (float*)d_ws;
  long long o = 0;
  auto af = [&](long long n) { float* p = ws + o; o += (n + 63) & ~63LL; return p; };
  auto au = [&](long long n) { return (u16*)af((n + 1) / 2); };

  float* s1      = af(BNv);
  float* s2      = af(BNv);
  float* dsum    = af(2 * NI);
  float* cs1v    = af(NI);
  float* cs2v    = af(NI);
  float* v2v     = af(NI);
  float* rb2ext  = af(128);
  float* rl2ext  = af(128);
  float* wcs     = af(64);
  // contiguous zero-init region: Zgl, sqv, stats(64), s2mU(16)
  float* zeroreg = af(ZERON);
  float* Zgl     = zeroreg;
  float* sqv     = zeroreg + BNv;
  float* stats   = zeroreg + 2 * BNv;
  unsigned* s2mU = (unsigned*)(stats + 64);
  u16* Tacc      = au(S2 * BATCH);   // bf16 now
  u16* emb2w_bf  = au(NN2);
  u16* h0aTb     = au(S1 * BATCH);   // [b][n][e]
  u16* ybf       = au(S1 * BATCH);   // y = attW^T @ h0a, [b][c][n]
  u16* hTb       = au(S1 * BATCH);   // [b][c][n]
  u16* xuaiTb    = au(S1 * BATCH);   // [b][n][c]
  u16* g1b       = au(NN2);
  u16* g2tb      = au(NN2);
  u16* G12b      = au(NN2);
  u16* Abig      = au((long long)BATCH * 128 * 2048);
  u16* stack4    = au(256 * 64);
  u16* uaiw_bf   = au(CE * CE);
  u16* attwT_bf  = au(CE * CE);
  u16* bigW      = au(BNN);  // 32 MB: gram W (att-p computed on the fly)

  // lap_rowsum also zero-inits the atomic region (no separate memset node)
  lap_rowsum<<<2048 + (ZERON + 255) / 256, 256, 0, stream>>>(gdata, dsum, zeroreg);

  mega_prep<<<10594, 256, 0, stream>>>(
      lin1_w, lin2_w, lin2_b, uai_w, att_W,
      stack4, rb2ext, rl2ext, uaiw_bf, attwT_bf, wcs,
      emb2_w, emb2w_bf, x, emb_w, emb_b, h0aTb,
      gdata, dsum, g2tb, g1b, cs1v);

  // G12t = (g1@g2)^T (blocks 0..511) + csv2 rows (blocks 512..1535) in one dispatch
  mgemm<32, 64, 15><<<1536, 256, 0, stream>>>(
      g2tb, g1b, nullptr, NI, NI, NI, NI, 0, 0,
      cs2v, G12b, NI, 0, cs1v, dsum + NI, gdata + NN2, nullptr, v2v);

  // y[b][c][n] = attW^T @ h0a  (K=64, tiny)
  mgemm<64, 64, 6><<<dim3(16, 1, BATCH), 256, 0, stream>>>(
      attwT_bf, h0aTb, nullptr, CE, CE, CE, CE, 0, S1,
      nullptr, ybf, NI, S1, nullptr, nullptr, nullptr, nullptr, nullptr);

  // hT[b][c][n'] = y @ emb2w^T + wcs (x) emb2_b; epilogue computes s1/s2/s2max
  mgemm<64, 32, 14><<<dim3(32, 1, BATCH), 256, 0, stream>>>(
      ybf, emb2w_bf, (const u16*)s2mU, NI, NI, NI, NI, S1, 0,
      s1, hTb, NI, S1, emb2_b, att_a, wcs, nullptr, s2);

  // fused two-stage: x_att = relu((p@h)/Z) then x_uai = x_att @ uaiw^T + uai_b
  mgemm<32, 64, 13><<<dim3(1, 32, BATCH), 256, 0, stream>>>(
      hTb, hTb, uaiw_bf, NI, NI, NI, NI, 0, S1,
      nullptr, xuaiTb, CE, S1, uai_b, s1, s2, (const float*)s2mU, sqv);

  // gram/gl weights (128x128 tiles; exp epilogue; rowsums into Zgl)
  mgemm<128, 128, 3><<<dim3(8, 8, BATCH), 256, 0, stream>>>(
      xuaiTb, xuaiTb, nullptr, CE, CE, CE, CE, S1, S1,
      nullptr, bigW, NI, NN2, sqv, nullptr, nullptr, nullptr, Zgl);

  // Abig = [[l1u/Z | L1L1u],[l2u/Z | L2L2u]] bf16 — l2 bias folded pre-division,
  // so its cc-contribution flows through the W-half GEMM (cc_kernel eliminated)
  mgemm<64, 64, 4><<<dim3(16, 4, BATCH), 256, 0, stream>>>(
      stack4, xuaiTb, nullptr, CE, CE, CE, CE, 0, S1,
      nullptr, Abig, 0, (long long)128 * 2048, Zgl, nullptr, rb2ext, nullptr, nullptr);

  // fused: Tacc(bf16) = Abig @ [W ; G12t] + b2 (x) cs2 + (L2 b2) (x) v2, + LN stats
  mgemm<64, 64, 5><<<dim3(16, 2, BATCH), 256, 0, stream>>>(
      Abig, bigW, G12b, NI, 2 * NI, 2048, NI, (long long)128 * 2048, NN2,
      nullptr, Tacc, NI, S2, cs2v, v2v, rb2ext, rl2ext, stats);

  ln_final_t<<<256, 256, 0, stream>>>(Tacc, stats, ln_w, ln_b, ct, xuaiTb, outp);
}